// Round 1
// baseline (66.330 us; speedup 1.0000x reference)
//
#include <hip/hip_runtime.h>

// Rasterize_51908974739476 — soft rasterizer forward on MI355X.
// Dtypes (established R0-R2): faces f32 (2,512,3,3), textures f32 (2,512,3,8),
// out f32 concat feature(2,9,192,192) | fim(2,192,192) | dmap(2,192,192);
// comparison is bf16-toleranced. det/w0/w1/w2 replicate numpy's f32
// expression order with fp-contract OFF so inside/argmin decisions match
// the reference bitwise.
//
// R4 -> R5 delta (binning split):
//   Timed iteration = ~40us harness workspace-poison fill (untouchable) +
//   ~22us raster. The raster's cost was dominated by 288 blocks EACH
//   staging 18KB + re-deriving all 512 face records (147k preps for 1k
//   unique faces) while the pixel loop only runs ~13 faces/tile.
//   Kernel A (2 blocks, 1 thread/face): derive record once, write packed
//   48B record + per-tile compacted face lists to workspace (poisoned each
//   iter anyway -> counts re-zeroed in-kernel).
//   Kernel B (12x12x2): load count + ~13 records into LDS, identical
//   exact-order pixel loop (no s_list indirection - lists pre-compacted).

namespace {
constexpr int BB = 2, FF = 512, HH = 192, WW = 192, TT = 8;
constexpr int TILE = 16;
constexpr int NTX = WW / TILE, NTY = HH / TILE, NTILES = NTX * NTY;  // 12,12,144
constexpr int HWSZ = HH * WW;
constexpr int RAW = FF * 9;  // 4608 floats of face data per batch
constexpr float NEARF = 0.5f, FARF = 100.0f, EPSF = 1e-8f;
// workspace byte offsets (total ~345 KB, ws is 256 MiB):
//   recs:   float [2][512][12]        @ 0       (49152 B), 16B-aligned recs
//   counts: int   [2][144]            @ 49152   (1152 B)
//   lists:  ushort[2][144][512]       @ 50304   (294912 B)
constexpr size_t WS_RECS = 0;
constexpr size_t WS_COUNTS = 49152;
constexpr size_t WS_LISTS = 50304;
}

// ---------------------------------------------------------------------------
// Kernel A: per-face record derivation + conservative tile binning.
// grid(BB), block(512) — one thread per face. Workspace counts are
// re-zeroed here every iteration (harness poisons ws between runs).
// ---------------------------------------------------------------------------
__global__ __launch_bounds__(512) void bin_faces_kernel(
    const float* __restrict__ faces,
    float* __restrict__ recs,
    int* __restrict__ counts,
    unsigned short* __restrict__ lists)
{
#pragma clang fp contract(off)
  const int b = blockIdx.x;
  const int f = threadIdx.x;  // 512 threads == FF faces
  int* cnts = counts + b * NTILES;
  if (f < NTILES) cnts[f] = 0;
  __syncthreads();  // zeroes visible (waitcnt+barrier) before atomics below

  const float* fp = faces + (size_t)b * RAW + (size_t)f * 9;
  const float x0 = fp[0], y0 = fp[1], z0 = fp[2];
  const float x1 = fp[3], y1 = fp[4], z1 = fp[5];
  const float x2 = fp[6], y2 = fp[7], z2 = fp[8];
  // exact reference expression order, contract off
  const float det = (x1 - x0) * (y2 - y0) - (x2 - x0) * (y1 - y0);
  const bool ok = fabsf(det) > EPSF;
  const float invdet = 1.0f / (ok ? det : 1.0f);

  // packed 48B record: x0 y0 x1 y1 | x2 y2 invdet iz0 | iz1 iz2 pad pad
  float4* dst = (float4*)(recs + ((size_t)b * FF + f) * 12);
  dst[0] = make_float4(x0, y0, x1, y1);
  dst[1] = make_float4(x2, y2, invdet, 1.0f / z0);
  dst[2] = make_float4(1.0f / z1, 1.0f / z2, 0.0f, 0.0f);
  if (!ok) return;

  // Conservative tile bbox. Pixel-center coord: px(w) = (2(w+.5)-W)/W
  // => w(px) = (px+1)*W/2 - 0.5. floor/ceil widening makes the cull
  // strictly conservative vs the closed-bbox pixel-center test (inside
  // implies within closed bbox), so no inside pixel's face is dropped.
  const float xmn = fminf(x0, fminf(x1, x2)), xmx = fmaxf(x0, fmaxf(x1, x2));
  const float ymn = fminf(y0, fminf(y1, y2)), ymx = fmaxf(y0, fmaxf(y1, y2));
  const int wlo = max(0, (int)floorf((xmn + 1.0f) * (0.5f * WW) - 0.5f));
  const int whi = min(WW - 1, (int)ceilf((xmx + 1.0f) * (0.5f * WW) - 0.5f));
  const int hlo = max(0, (int)floorf((ymn + 1.0f) * (0.5f * HH) - 0.5f));
  const int hhi = min(HH - 1, (int)ceilf((ymx + 1.0f) * (0.5f * HH) - 0.5f));
  if (whi < wlo || hhi < hlo) return;
  const int tx0 = wlo / TILE, tx1 = whi / TILE;
  const int ty0 = hlo / TILE, ty1 = hhi / TILE;
  for (int ty = ty0; ty <= ty1; ++ty) {
    for (int tx = tx0; tx <= tx1; ++tx) {
      const int t = ty * NTX + tx;
      const int slot = atomicAdd(&cnts[t], 1);  // device-scope, ~1.8k total
      lists[((size_t)b * NTILES + t) * FF + slot] = (unsigned short)f;
    }
  }
}

// ---------------------------------------------------------------------------
// Kernel B: per-tile render. grid(12,12,2), block(16,16).
// Stages only this tile's compacted records (~13 avg, <=512 worst) into LDS.
// ---------------------------------------------------------------------------
__global__ __launch_bounds__(256) void render_kernel(
    const float* __restrict__ recs,
    const int* __restrict__ counts,
    const unsigned short* __restrict__ lists,
    const float* __restrict__ textures,
    float* __restrict__ out)
{
#pragma clang fp contract(off)
  __shared__ float sface[FF * 12];  // 24 KB worst case (cnt <= FF)

  const int tx = threadIdx.x, ty = threadIdx.y;
  const int tid = ty * TILE + tx;
  const int bx = blockIdx.x, by = blockIdx.y, b = blockIdx.z;
  const int tile = by * NTX + bx;

  const int cnt = counts[b * NTILES + tile];
  const unsigned short* lst = lists + ((size_t)b * NTILES + tile) * FF;

  // Stage compacted records; stash face id in the pad slot (r2.z).
  for (int i = tid; i < cnt; i += 256) {
    const int f = lst[i];
    const float4* src = (const float4*)(recs + ((size_t)b * FF + f) * 12);
    float4 r0 = src[0];
    float4 r1 = src[1];
    float4 r2 = src[2];
    r2.z = (float)f;  // f < 512, exact in f32
    float4* dst = (float4*)(sface + i * 12);
    dst[0] = r0; dst[1] = r1; dst[2] = r2;
  }
  __syncthreads();

  const int w = bx * TILE + tx;
  const int h = by * TILE + ty;
  const float px = (2.0f * ((float)w + 0.5f) - (float)WW) / (float)WW;
  const float py = (2.0f * ((float)h + 0.5f) - (float)HH) / (float)HH;

  float best = FARF;
  int bestf = 0;
  float bw0 = 0.0f, bw1 = 0.0f, bw2 = 0.0f;

  if (cnt > 0) {
    // prefetch record 0 (broadcast vector LDS reads — conflict-free)
    float4 r0 = *(const float4*)(sface + 0);
    float4 r1 = *(const float4*)(sface + 4);
    float4 r2 = *(const float4*)(sface + 8);
    for (int i = 0; i < cnt; ++i) {
      const float4 c0 = r0; const float4 c1 = r1; const float4 c2 = r2;
      if (i + 1 < cnt) {  // prefetch next record while computing current
        const float* p = sface + (size_t)(i + 1) * 12;
        r0 = *(const float4*)(p);
        r1 = *(const float4*)(p + 4);
        r2 = *(const float4*)(p + 8);
      }
      // c0 = {x0,y0,x1,y1}  c1 = {x2,y2,invdet,iz0}  c2 = {iz1,iz2,fid,-}
      // Replicate reference expression order exactly (contract off).
      float dx0 = c0.x - px, dy0 = c0.y - py;
      float dx1 = c0.z - px, dy1 = c0.w - py;
      float dx2 = c1.x - px, dy2 = c1.y - py;
      float w0 = (dx1 * dy2 - dx2 * dy1) * c1.z;
      float w1 = (dx2 * dy0 - dx0 * dy2) * c1.z;
      float w2 = 1.0f - w0 - w1;
      if (w0 >= 0.0f && w1 >= 0.0f && w2 >= 0.0f) {
        // 1/z precomputed: <=1ulp vs ref's w/z — cannot flip argmin on
        // continuous data; dmap tolerance is huge vs that.
        float invd = w0 * c1.w + w1 * c2.x + w2 * c2.y;
        if (invd > EPSF) {
          float d = 1.0f / invd;
          if (d >= NEARF && d <= FARF && d < best) {  // strict < == argmin-first
            best = d; bestf = (int)c2.z;
            bw0 = w0; bw1 = w1; bw2 = w2;
          }
        }
      }
    }
  }

  const bool covered = best < FARF;
  const size_t pix = (size_t)h * WW + w;
  float* featp = out + (size_t)b * 9 * HWSZ + pix;
  if (covered) {
    const float4* tp = (const float4*)(textures + (size_t)(b * FF + bestf) * 3 * TT);  // 96B rec
    float4 t0 = tp[0], t1 = tp[1];  // vertex 0, channels 0..7
    float4 t2 = tp[2], t3 = tp[3];  // vertex 1
    float4 t4 = tp[4], t5 = tp[5];  // vertex 2
    float a0[8] = {t0.x, t0.y, t0.z, t0.w, t1.x, t1.y, t1.z, t1.w};
    float a1[8] = {t2.x, t2.y, t2.z, t2.w, t3.x, t3.y, t3.z, t3.w};
    float a2[8] = {t4.x, t4.y, t4.z, t4.w, t5.x, t5.y, t5.z, t5.w};
    #pragma unroll
    for (int t = 0; t < TT; ++t) {
      float v = bw0 * a0[t] + bw1 * a1[t];  // einsum k-order, contract off
      v = v + bw2 * a2[t];
      featp[(size_t)t * HWSZ] = v;
    }
    featp[(size_t)TT * HWSZ] = 1.0f;  // mask channel
  } else {
    #pragma unroll
    for (int t = 0; t < TT + 1; ++t) featp[(size_t)t * HWSZ] = 0.0f;
  }

  const size_t fim_base = (size_t)BB * 9 * HWSZ;          // 663552
  const size_t dmap_base = fim_base + (size_t)BB * HWSZ;  // 737280
  out[fim_base + (size_t)b * HWSZ + pix] = covered ? (float)bestf : -1.0f;
  out[dmap_base + (size_t)b * HWSZ + pix] = best;  // FAR if uncovered
}

extern "C" void kernel_launch(void* const* d_in, const int* in_sizes, int n_in,
                              void* d_out, int out_size, void* d_ws, size_t ws_size,
                              hipStream_t stream) {
  (void)in_sizes; (void)n_in; (void)out_size; (void)ws_size;
  const float* faces = (const float*)d_in[0];
  const float* textures = (const float*)d_in[1];
  float* out = (float*)d_out;

  float* recs = (float*)((char*)d_ws + WS_RECS);
  int* counts = (int*)((char*)d_ws + WS_COUNTS);
  unsigned short* lists = (unsigned short*)((char*)d_ws + WS_LISTS);

  hipLaunchKernelGGL(bin_faces_kernel, dim3(BB), dim3(512), 0, stream,
                     faces, recs, counts, lists);
  hipLaunchKernelGGL(render_kernel, dim3(NTX, NTY, BB), dim3(TILE, TILE), 0, stream,
                     recs, counts, lists, textures, out);
}

// Round 2
// 62.202 us; speedup vs baseline: 1.0664x; 1.0664x over previous
//
#include <hip/hip_runtime.h>

// Rasterize_51908974739476 — soft rasterizer forward on MI355X.
// Dtypes (established R0-R2): faces f32 (2,512,3,3), textures f32 (2,512,3,8),
// out f32 concat feature(2,9,192,192) | fim(2,192,192) | dmap(2,192,192);
// comparison is bf16-toleranced. det/w0/w1/w2 replicate numpy's f32
// expression order with fp-contract OFF so inside/argmin decisions match
// the reference bitwise.
//
// R5 -> R6 deltas (post-mortem: 2-dispatch split REGRESSED 62.6->66.3; the
// raster portion is dispatch-overhead + block-serial-latency bound, not
// prep-arithmetic bound):
//   (1) back to ONE dispatch (the second dependent launch cost more than the
//       prep it saved),
//   (2) tile 16x24 -> grid 12x8x2 = 192 blocks <= 256 CUs: every CU runs
//       exactly one block, eliminating R4's 2x serial tail on 32 CUs,
//   (3) no raw-LDS staging: direct global face reads (thread f reads 36B at
//       f*36 -> fully contiguous 2.3KB/wave), saving 18KB LDS + 1 barrier,
//   (4) ballot wave-compaction (1 LDS atomic per wave instead of 512
//       serialized same-address atomics), records written pre-compacted so
//       the pixel loop has no s_list indirection.

namespace {
constexpr int BB = 2, FF = 512, HH = 192, WW = 192, TT = 8;
constexpr int TW = 16, TH = 24;            // tile 16 wide x 24 tall
constexpr int NTHR = TW * TH;              // 384 threads = 6 waves
constexpr int HWSZ = HH * WW;
constexpr float NEARF = 0.5f, FARF = 100.0f, EPSF = 1e-8f;
}

__global__ __launch_bounds__(NTHR) void raster_fused_kernel(
    const float* __restrict__ faces,
    const float* __restrict__ textures,
    float* __restrict__ out)
{
#pragma clang fp contract(off)
  __shared__ float sface[FF * 12];  // 24 KB, compacted records
  __shared__ int s_count;

  const int tx = threadIdx.x, ty = threadIdx.y;
  const int tid = ty * TW + tx;
  const int lane = tid & 63;
  const int bx = blockIdx.x, by = blockIdx.y, b = blockIdx.z;

  if (tid == 0) s_count = 0;

  // Tile pixel-center bounds in NDC (same formula as reference px/py)
  const float px_lo = (2.0f * ((float)(bx * TW) + 0.5f) - (float)WW) / (float)WW;
  const float px_hi = (2.0f * ((float)(bx * TW + TW - 1) + 0.5f) - (float)WW) / (float)WW;
  const float py_lo = (2.0f * ((float)(by * TH) + 0.5f) - (float)HH) / (float)HH;
  const float py_hi = (2.0f * ((float)(by * TH + TH - 1) + 0.5f) - (float)HH) / (float)HH;

  __syncthreads();  // s_count = 0 visible before compaction atomics

  // --- derive per-face constants + bbox-cull + ballot compaction ---
  // f = tid .. : iteration 1 covers f 0..383 (all 6 waves fully active),
  // iteration 2 covers f 384..511 (waves 0,1 fully active) -> every wave is
  // uniformly active or inactive, so lane-0 broadcast is safe.
  for (int f = tid; f < FF; f += NTHR) {
    const float* fp = faces + (size_t)b * (FF * 9) + (size_t)f * 9;
    const float x0 = fp[0], y0 = fp[1], z0 = fp[2];
    const float x1 = fp[3], y1 = fp[4], z1 = fp[5];
    const float x2 = fp[6], y2 = fp[7], z2 = fp[8];
    // exact reference expression order, contract off
    const float det = (x1 - x0) * (y2 - y0) - (x2 - x0) * (y1 - y0);
    const bool ok = fabsf(det) > EPSF;
    const float invdet = 1.0f / (ok ? det : 1.0f);
    bool pass = false;
    if (ok) {
      const float xmn = fminf(x0, fminf(x1, x2)), xmx = fmaxf(x0, fmaxf(x1, x2));
      const float ymn = fminf(y0, fminf(y1, y2)), ymx = fmaxf(y0, fmaxf(y1, y2));
      // inside => pixel center within closed bbox => cull is exact
      pass = (xmx >= px_lo && xmn <= px_hi && ymx >= py_lo && ymn <= py_hi);
    }
    const unsigned long long m = __ballot(pass);
    const int wtotal = __popcll(m);
    int wbase = 0;
    if (lane == 0 && wtotal) wbase = atomicAdd(&s_count, wtotal);
    wbase = __shfl(wbase, 0);
    if (pass) {
      const int slot = wbase + __popcll(m & ((1ull << lane) - 1ull));
      // packed 48B record: x0 y0 x1 y1 | x2 y2 invdet iz0 | iz1 iz2 fid pad
      float* dst = sface + slot * 12;
      ((float4*)dst)[0] = make_float4(x0, y0, x1, y1);
      ((float4*)dst)[1] = make_float4(x2, y2, invdet, 1.0f / z0);
      ((float4*)dst)[2] = make_float4(1.0f / z1, 1.0f / z2, (float)f, 0.0f);
    }
  }
  __syncthreads();

  const int w = bx * TW + tx;
  const int h = by * TH + ty;
  const float px = (2.0f * ((float)w + 0.5f) - (float)WW) / (float)WW;
  const float py = (2.0f * ((float)h + 0.5f) - (float)HH) / (float)HH;

  float best = FARF;
  int bestf = 0;
  float bw0 = 0.0f, bw1 = 0.0f, bw2 = 0.0f;
  const int cnt = s_count;

  if (cnt > 0) {
    // prefetch record 0 (broadcast vector LDS reads — conflict-free)
    float4 r0 = *(const float4*)(sface + 0);
    float4 r1 = *(const float4*)(sface + 4);
    float4 r2 = *(const float4*)(sface + 8);
    for (int i = 0; i < cnt; ++i) {
      const float4 c0 = r0; const float4 c1 = r1; const float4 c2 = r2;
      if (i + 1 < cnt) {  // prefetch next record while computing current
        const float* p = sface + (size_t)(i + 1) * 12;
        r0 = *(const float4*)(p);
        r1 = *(const float4*)(p + 4);
        r2 = *(const float4*)(p + 8);
      }
      // c0 = {x0,y0,x1,y1}  c1 = {x2,y2,invdet,iz0}  c2 = {iz1,iz2,fid,-}
      // Replicate reference expression order exactly (contract off).
      float dx0 = c0.x - px, dy0 = c0.y - py;
      float dx1 = c0.z - px, dy1 = c0.w - py;
      float dx2 = c1.x - px, dy2 = c1.y - py;
      float w0 = (dx1 * dy2 - dx2 * dy1) * c1.z;
      float w1 = (dx2 * dy0 - dx0 * dy2) * c1.z;
      float w2 = 1.0f - w0 - w1;
      if (w0 >= 0.0f && w1 >= 0.0f && w2 >= 0.0f) {
        // 1/z precomputed: <=1ulp vs ref's w/z — cannot flip argmin on
        // continuous data; dmap tolerance is huge vs that.
        float invd = w0 * c1.w + w1 * c2.x + w2 * c2.y;
        if (invd > EPSF) {
          float d = 1.0f / invd;
          if (d >= NEARF && d <= FARF && d < best) {  // strict < == argmin-first
            best = d; bestf = (int)c2.z;
            bw0 = w0; bw1 = w1; bw2 = w2;
          }
        }
      }
    }
  }

  const bool covered = best < FARF;
  const size_t pix = (size_t)h * WW + w;
  float* featp = out + (size_t)b * 9 * HWSZ + pix;
  if (covered) {
    const float4* tp = (const float4*)(textures + (size_t)(b * FF + bestf) * 3 * TT);  // 96B rec
    float4 t0 = tp[0], t1 = tp[1];  // vertex 0, channels 0..7
    float4 t2 = tp[2], t3 = tp[3];  // vertex 1
    float4 t4 = tp[4], t5 = tp[5];  // vertex 2
    float a0[8] = {t0.x, t0.y, t0.z, t0.w, t1.x, t1.y, t1.z, t1.w};
    float a1[8] = {t2.x, t2.y, t2.z, t2.w, t3.x, t3.y, t3.z, t3.w};
    float a2[8] = {t4.x, t4.y, t4.z, t4.w, t5.x, t5.y, t5.z, t5.w};
    #pragma unroll
    for (int t = 0; t < TT; ++t) {
      float v = bw0 * a0[t] + bw1 * a1[t];  // einsum k-order, contract off
      v = v + bw2 * a2[t];
      featp[(size_t)t * HWSZ] = v;
    }
    featp[(size_t)TT * HWSZ] = 1.0f;  // mask channel
  } else {
    #pragma unroll
    for (int t = 0; t < TT + 1; ++t) featp[(size_t)t * HWSZ] = 0.0f;
  }

  const size_t fim_base = (size_t)BB * 9 * HWSZ;          // 663552
  const size_t dmap_base = fim_base + (size_t)BB * HWSZ;  // 737280
  out[fim_base + (size_t)b * HWSZ + pix] = covered ? (float)bestf : -1.0f;
  out[dmap_base + (size_t)b * HWSZ + pix] = best;  // FAR if uncovered
}

extern "C" void kernel_launch(void* const* d_in, const int* in_sizes, int n_in,
                              void* d_out, int out_size, void* d_ws, size_t ws_size,
                              hipStream_t stream) {
  (void)in_sizes; (void)n_in; (void)out_size; (void)d_ws; (void)ws_size;
  const float* faces = (const float*)d_in[0];
  const float* textures = (const float*)d_in[1];
  float* out = (float*)d_out;
  dim3 grid(WW / TW, HH / TH, BB);  // 12 x 8 x 2 = 192 blocks (<= 256 CUs)
  dim3 block(TW, TH, 1);            // 384 threads = 6 waves
  hipLaunchKernelGGL(raster_fused_kernel, grid, block, 0, stream,
                     faces, textures, out);
}